// Round 1
// baseline (162.534 us; speedup 1.0000x reference)
//
#include <hip/hip_runtime.h>
#include <hip/hip_bf16.h>
#include <math.h>

#define Bn 8
#define Tn 2048
#define Cn 384
#define Hn 64
#define SCALE2 0.07362241f            // 384^-0.5 * log2(e): exp(x*scale) = 2^(x*SCALE2)

using bf16x8 = __attribute__((ext_vector_type(8))) short;  // 8 bf16 = 4 VGPRs
using f32x4  = __attribute__((ext_vector_type(4))) float;
using u32x4  = __attribute__((ext_vector_type(4))) unsigned;

#define MFMA(a, b, c) __builtin_amdgcn_mfma_f32_16x16x32_bf16((a), (b), (c), 0, 0, 0)

static __device__ __forceinline__ short f2bf(float f) {  // RNE fp32->bf16
  unsigned u = __float_as_uint(f);
  u += 0x7fffu + ((u >> 16) & 1u);
  return (short)(u >> 16);
}
static __device__ __forceinline__ float bf2f(short s) {
  return __uint_as_float(((unsigned)(unsigned short)s) << 16);
}
static __device__ __forceinline__ float fexp2(float x) {  // v_exp_f32 (base-2)
#if __has_builtin(__builtin_amdgcn_exp2f)
  return __builtin_amdgcn_exp2f(x);
#else
  return exp2f(x);
#endif
}
static __device__ __forceinline__ unsigned pack2(float lo, float hi) {
  return (unsigned)(unsigned short)f2bf(lo) | ((unsigned)(unsigned short)f2bf(hi) << 16);
}

// ---------------- K0: W -> WbT (192 x 384) bf16, row n = output col ---------
__global__ __launch_bounds__(256) void wconv_kernel(
    const float* __restrict__ Wq, const float* __restrict__ Wk,
    const float* __restrict__ Wv, short* __restrict__ WbT) {
  int idx = blockIdx.x * 256 + threadIdx.x;  // n*384 + k, 73728 total
  int n = idx / 384, k = idx - n * 384;
  const float* W = (n < 64) ? Wq : (n < 128) ? Wk : Wv;
  WbT[idx] = f2bf(W[k * 64 + (n & 63)]);
}

// ---------------- K1: proj GEMM, 16-row tiles (1024 blocks, 4/CU) -----------
__global__ __launch_bounds__(256) void proj_kernel(
    const float* __restrict__ x, const short* __restrict__ WbT,
    short* __restrict__ qb, short* __restrict__ kb, short* __restrict__ vT) {
  __shared__ short xs[16][392];    // stride 392: banks 2-way (free)
  __shared__ short vtile[64][20];  // v-tile transpose bounce
  const int tid = threadIdx.x;
  const int t0 = blockIdx.x * 16;  // global row (b*2048 + t)
  const float* xb = x + (size_t)t0 * Cn;
  #pragma unroll
  for (int i = 0; i < 6; ++i) {
    int j = tid + i * 256;  // float4 index, 1536 total
    int row = j / 96, colv = (j - row * 96) * 4;
    float4 v = *(const float4*)(xb + row * Cn + colv);
    short4 s4; s4.x = f2bf(v.x); s4.y = f2bf(v.y); s4.z = f2bf(v.z); s4.w = f2bf(v.w);
    *(short4*)(&xs[row][colv]) = s4;
  }
  __syncthreads();
  const int w = tid >> 6, l15 = tid & 15, quad = (tid & 63) >> 4;
  f32x4 acc[3] = {};
  for (int ks = 0; ks < 12; ++ks) {
    bf16x8 a = *(const bf16x8*)(&xs[l15][ks * 32 + quad * 8]);
    #pragma unroll
    for (int cf = 0; cf < 3; ++cf) {
      bf16x8 bfr = *(const bf16x8*)(WbT + (size_t)(48 * w + 16 * cf + l15) * Cn + ks * 32 + quad * 8);
      acc[cf] = MFMA(a, bfr, acc[cf]);
    }
  }
  #pragma unroll
  for (int cf = 0; cf < 3; ++cf) {
    int cbase = 48 * w + 16 * cf, c = cbase + l15;
    #pragma unroll
    for (int r = 0; r < 4; ++r) {
      int row = t0 + quad * 4 + r;
      short val = f2bf(acc[cf][r]);
      if (cbase < 64)       qb[(size_t)row * Hn + c] = val;
      else if (cbase < 128) kb[(size_t)row * Hn + (c - 64)] = val;
      else                  vtile[c - 128][quad * 4 + r] = val;
    }
  }
  __syncthreads();
  const int b = t0 >> 11, t0l = t0 & 2047;
  int h = tid >> 2, tseg = (tid & 3) * 4;
  *(short4*)(vT + ((size_t)(b * Hn + h)) * Tn + t0l + tseg) =
      *(const short4*)(&vtile[h][tseg]);
}

// ---------------- K2: balanced column exp-sums -> pL partials (NO E store) --
// Pair (colchunk j: 32-j t-groups) with (colchunk 31-j: j+1 t-groups) = 33.
// unit = ((b*16 + j)*8 + u): u-th eighth of the pair's 33 t-group list.
// 3-deep A-frag prefetch (A/B/C buffers): 2 chunk-loads in flight per comp.
__global__ __launch_bounds__(256) void colstats_kernel(
    const short* __restrict__ qb, const short* __restrict__ kb,
    float* __restrict__ pL) {
  const int unit = blockIdx.x;
  const int b = unit >> 7, rem = unit & 127;
  const int j = rem >> 3, u = rem & 7;
  const int lo = (u * 33) >> 3, hi = ((u + 1) * 33) >> 3;  // 4 or 5 entries
  const int big = 32 - j;
  const int tid = threadIdx.x, w = tid >> 6, l15 = tid & 15, quad = (tid & 63) >> 4;
  __shared__ float redl[64][17];

  auto run = [&](const int i, const int k0, const int k1, const int slot) {
    const int s0 = i << 6;
    float l[4] = {0.f, 0.f, 0.f, 0.f};
    const int n = k1 - k0;
    if (n > 0) {                           // block-uniform: barrier-safe
      bf16x8 bk[8];
      #pragma unroll
      for (int nf = 0; nf < 4; ++nf) {
        const size_t krow = (size_t)(b * Tn + s0 + 16 * nf + l15) * Hn;
        bk[2 * nf]     = *(const bf16x8*)(kb + krow + quad * 8);
        bk[2 * nf + 1] = *(const bf16x8*)(kb + krow + 32 + quad * 8);
      }
      auto cload = [&](bf16x8& A0, bf16x8& A1, int k) {
        size_t ar = (size_t)(b * Tn + ((i + k) << 6) + 16 * w + l15) * Hn;
        A0 = *(const bf16x8*)(qb + ar + quad * 8);
        A1 = *(const bf16x8*)(qb + ar + 32 + quad * 8);
      };
      auto ccomp = [&](bf16x8 A0, bf16x8 A1, int k) {
        f32x4 sc[4] = {};
        #pragma unroll
        for (int nf = 0; nf < 4; ++nf) {
          sc[nf] = MFMA(A0, bk[2 * nf], sc[nf]);
          sc[nf] = MFMA(A1, bk[2 * nf + 1], sc[nf]);
        }
        const bool diag = (k == 0);
        const int tb = ((i + k) << 6) + 16 * w + quad * 4;
        #pragma unroll
        for (int nf = 0; nf < 4; ++nf) {
          int s = s0 + 16 * nf + l15;
          #pragma unroll
          for (int r = 0; r < 4; ++r) {
            float v = sc[nf][r] * SCALE2;            // exp2-domain score
            if (diag && (tb + r) < s) v = -INFINITY; // exp2(-inf) = 0
            l[nf] += fexp2(v);
          }
        }
      };
      bf16x8 a0A, a1A, a0B, a1B, a0C, a1C;
      cload(a0A, a1A, k0);
      if (n > 1) cload(a0B, a1B, k0 + 1);
      if (n > 2) cload(a0C, a1C, k0 + 2);
      int k = k0;
      while (k + 3 < k1) {  // 3x unrolled steady state, 2 loads in flight
        ccomp(a0A, a1A, k);     cload(a0A, a1A, k + 3);
        ccomp(a0B, a1B, k + 1); if (k + 4 < k1) cload(a0B, a1B, k + 4);
        ccomp(a0C, a1C, k + 2); if (k + 5 < k1) cload(a0C, a1C, k + 5);
        k += 3;
      }
      const int rem2 = k1 - k;
      if (rem2 > 0) ccomp(a0A, a1A, k);
      if (rem2 > 1) ccomp(a0B, a1B, k + 1);
      if (rem2 > 2) ccomp(a0C, a1C, k + 2);
    }
    __syncthreads();  // protect redl reuse across phases
    #pragma unroll
    for (int nf = 0; nf < 4; ++nf) redl[16 * nf + l15][w * 4 + quad] = l[nf];
    __syncthreads();
    if (tid < 64) {
      float ls = 0.f;
      #pragma unroll
      for (int q2 = 0; q2 < 16; ++q2) ls += redl[tid][q2];
      pL[unit * 128 + slot * 64 + tid] = ls;
    }
  };
  run(j, lo, min(hi, big), 0);                       // big member: colchunk j
  run(31 - j, max(lo, big) - big, hi - big, 1);      // small: colchunk 31-j
}

// ---------------- K3: vS[h][s] = vT[h][s] / L[s]; also zeroes out -----------
// L[s] = sum over the 8 units of column-chunk s's pair (slot by membership).
__global__ __launch_bounds__(256) void vhat_kernel(
    const short* __restrict__ vT, const float* __restrict__ pL,
    short* __restrict__ vS, float* __restrict__ outz) {
  int gid = blockIdx.x * 256 + threadIdx.x;  // 131072 threads x 8 elems
  size_t base = (size_t)gid * 8;
  int b = (int)(base >> 17), s = (int)(base & 2047);
  int i = s >> 6, c = s & 63;
  int j2 = (i < 16) ? i : 31 - i;
  int slot = (i < 16) ? 0 : 1;
  const float* pp = pL + (size_t)((b * 16 + j2) * 8) * 128 + slot * 64 + c;
  float L0x = 0.f, L0y = 0.f, L0z = 0.f, L0w = 0.f;
  float L1x = 0.f, L1y = 0.f, L1z = 0.f, L1w = 0.f;
  #pragma unroll
  for (int u = 0; u < 8; ++u) {
    float4 p0 = *(const float4*)(pp + u * 128);
    float4 p1 = *(const float4*)(pp + u * 128 + 4);
    L0x += p0.x; L0y += p0.y; L0z += p0.z; L0w += p0.w;
    L1x += p1.x; L1y += p1.y; L1z += p1.z; L1w += p1.w;
  }
  short4 v0 = *(const short4*)(vT + base);
  short4 v1 = *(const short4*)(vT + base + 4);
  short4 r0, r1;
  r0.x = f2bf(bf2f(v0.x) / L0x); r0.y = f2bf(bf2f(v0.y) / L0y);
  r0.z = f2bf(bf2f(v0.z) / L0z); r0.w = f2bf(bf2f(v0.w) / L0w);
  r1.x = f2bf(bf2f(v1.x) / L1x); r1.y = f2bf(bf2f(v1.y) / L1y);
  r1.z = f2bf(bf2f(v1.z) / L1z); r1.w = f2bf(bf2f(v1.w) / L1w);
  *(short4*)(vS + base) = r0;
  *(short4*)(vS + base + 4) = r1;
  float4 z = {0.f, 0.f, 0.f, 0.f};   // fold out-memset: same 1M-float extent
  *(float4*)(outz + base) = z;
  *(float4*)(outz + base + 4) = z;
}

// ---------------- K4: FUSED out = exp(QK^T)_tri . vS^T, no E materialization -
// Pair (tile 31-j: 32-j chunks) with (tile j: j+1 chunks) = 33 chunks.
// unit = ((b*16 + j)*8 + u): u-th eighth of the pair's chunk list.
// Per chunk per wave: 8 MFMA S^T=K.Q (lane&15 = t), mask+exp2, bf16-pack,
// per-wave XOR-swizzled LDS transpose (no barriers), 8 MFMA PV, atomic flush.
__global__ __launch_bounds__(256) void outg_kernel(
    const short* __restrict__ qb, const short* __restrict__ kb,
    const short* __restrict__ vS, float* __restrict__ out) {
  const int unit = blockIdx.x;
  const int b = unit >> 7, rem = unit & 127;
  const int j = rem >> 3, u = rem & 7;
  const int lo = (u * 33) >> 3, hi = ((u + 1) * 33) >> 3;  // 4 or 5 chunks
  const int big = 32 - j;                                   // chunks in big member
  const int tid = threadIdx.x, w = tid >> 6, l15 = tid & 15, quad = (tid & 63) >> 4;
  __shared__ unsigned plds_raw[4][512];    // per-wave 2KB P tile [16 t][64 s] bf16
  char* pw = (char*)(&plds_raw[w][0]);
  // XOR swizzle: byte ^= (l15&7)<<4 breaks the 128B-row same-bank pattern.
  const int swz = (l15 & 7) << 4;
  int wroff[8];                            // write offsets: s = 16nf+4q+{2p,2p+1}
  #pragma unroll
  for (int nf = 0; nf < 4; ++nf)
    #pragma unroll
    for (int p = 0; p < 2; ++p)
      wroff[2 * nf + p] = l15 * 128 + ((nf * 32 + quad * 8 + p * 4) ^ swz);
  const int rd0 = l15 * 128 + ((quad * 16) ^ swz);        // s = 8q..8q+7
  const int rd1 = l15 * 128 + ((64 + quad * 16) ^ swz);   // s = 32+8q..+7
  const size_t QKbase = (size_t)b * Tn * Hn;
  const size_t Vbase  = (size_t)b * Hn * Tn;

  auto run = [&](const int tile, const int k0, const int k1) {
    if (k0 >= k1) return;
    const int tbase = (tile << 6) + 16 * w;
    const size_t qrow = QKbase + (size_t)(tbase + l15) * Hn;
    const bf16x8 qf0 = *(const bf16x8*)(qb + qrow + quad * 8);       // B[n=t][k=h]
    const bf16x8 qf1 = *(const bf16x8*)(qb + qrow + 32 + quad * 8);
    const int tg = tbase + l15;            // this lane's query row t
    f32x4 acc[4] = {};
    bf16x8 kf[8];
    auto loadK = [&](int ch) {             // A[m=s][k=h] frags for S^T
      const int s0 = ch << 6;
      #pragma unroll
      for (int nf = 0; nf < 4; ++nf) {
        const size_t kr = QKbase + (size_t)(s0 + 16 * nf + l15) * Hn;
        kf[2 * nf]     = *(const bf16x8*)(kb + kr + quad * 8);
        kf[2 * nf + 1] = *(const bf16x8*)(kb + kr + 32 + quad * 8);
      }
    };
    loadK(k0);
    for (int ch = k0; ch < k1; ++ch) {
      const int s0 = ch << 6;
      f32x4 sc[4] = {};                    // D[s][t]: lane&15 = t, s = 16nf+4q+r
      #pragma unroll
      for (int nf = 0; nf < 4; ++nf) {
        sc[nf] = MFMA(kf[2 * nf], qf0, sc[nf]);
        sc[nf] = MFMA(kf[2 * nf + 1], qf1, sc[nf]);
      }
      if (ch + 1 < k1) loadK(ch + 1);      // prefetch next chunk (kf dead here)
      bf16x8 vf[8];                        // B[n=h][k=s] frags, L2-hot
      #pragma unroll
      for (int nf = 0; nf < 4; ++nf) {
        const size_t vr = Vbase + (size_t)(16 * nf + l15) * Tn + s0;
        vf[2 * nf]     = *(const bf16x8*)(vS + vr + quad * 8);
        vf[2 * nf + 1] = *(const bf16x8*)(vS + vr + 32 + quad * 8);
      }
      const bool diag = (ch == tile);
      #pragma unroll
      for (int nf = 0; nf < 4; ++nf) {
        float ev[4];
        #pragma unroll
        for (int r = 0; r < 4; ++r) {
          float v = sc[nf][r] * SCALE2;
          const int s = s0 + 16 * nf + quad * 4 + r;
          if (diag && tg < s) v = -INFINITY;         // causal: exp2(-inf)=0
          ev[r] = fexp2(v);
        }
        *(unsigned*)(pw + wroff[2 * nf])     = pack2(ev[0], ev[1]);
        *(unsigned*)(pw + wroff[2 * nf + 1]) = pack2(ev[2], ev[3]);
      }
      __asm__ __volatile__("" ::: "memory");  // order LDS write->read (TBAA guard)
      const bf16x8 a0 = __builtin_bit_cast(bf16x8, *(const u32x4*)(pw + rd0));
      const bf16x8 a1 = __builtin_bit_cast(bf16x8, *(const u32x4*)(pw + rd1));
      #pragma unroll
      for (int nf = 0; nf < 4; ++nf) {     // D[t][h]: lane&15 = h, t = 4q+r
        acc[nf] = MFMA(a0, vf[2 * nf], acc[nf]);
        acc[nf] = MFMA(a1, vf[2 * nf + 1], acc[nf]);
      }
    }
    #pragma unroll
    for (int nf = 0; nf < 4; ++nf)
      #pragma unroll
      for (int r = 0; r < 4; ++r)
        atomicAdd(&out[QKbase + (size_t)(tbase + quad * 4 + r) * Hn + 16 * nf + l15],
                  acc[nf][r]);
  };
  run(31 - j, lo, min(hi, big));              // big member: tile 31-j
  run(j, max(lo, big) - big, hi - big);       // small member: tile j
}

extern "C" void kernel_launch(void* const* d_in, const int* in_sizes, int n_in,
                              void* d_out, int out_size, void* d_ws, size_t ws_size,
                              hipStream_t stream) {
  const float* x  = (const float*)d_in[0];
  const float* Wq = (const float*)d_in[1];
  const float* Wk = (const float*)d_in[2];
  const float* Wv = (const float*)d_in[3];
  char* ws = (char*)d_ws;                          // needs ~9.1 MB (Eb eliminated)
  short* qb   = (short*)(ws);                      // 2 MB (T,H)
  short* kb   = (short*)(ws + 2097152);            // 2 MB (T,H)
  short* vT   = (short*)(ws + 4194304);            // 2 MB (H,T)
  short* vS   = (short*)(ws + 6291456);            // 2 MB (H,T) v/L
  short* WbT  = (short*)(ws + 8388608);            // 144 KB
  float* pL   = (float*)(ws + 8536064);            // 512 KB unit partial sums
  float* outp = (float*)d_out;

  hipLaunchKernelGGL(wconv_kernel, dim3(288), dim3(256), 0, stream, Wq, Wk, Wv, WbT);
  hipLaunchKernelGGL(proj_kernel, dim3(Bn * Tn / 16), dim3(256), 0, stream, x, WbT, qb, kb, vT);
  hipLaunchKernelGGL(colstats_kernel, dim3(1024), dim3(256), 0, stream, qb, kb, pL);
  hipLaunchKernelGGL(vhat_kernel, dim3(512), dim3(256), 0, stream, vT, pL, vS, outp);
  hipLaunchKernelGGL(outg_kernel, dim3(1024), dim3(256), 0, stream, qb, kb, vS, outp);
}

// Round 2
// 147.500 us; speedup vs baseline: 1.1019x; 1.1019x over previous
//
#include <hip/hip_runtime.h>
#include <hip/hip_bf16.h>
#include <math.h>

#define Bn 8
#define Tn 2048
#define Cn 384
#define Hn 64
#define SCALE2 0.07362241f            // 384^-0.5 * log2(e): exp(x*scale) = 2^(x*SCALE2)

using bf16x8 = __attribute__((ext_vector_type(8))) short;  // 8 bf16 = 4 VGPRs
using f32x4  = __attribute__((ext_vector_type(4))) float;
using u32x4  = __attribute__((ext_vector_type(4))) unsigned;

#define MFMA(a, b, c) __builtin_amdgcn_mfma_f32_16x16x32_bf16((a), (b), (c), 0, 0, 0)

static __device__ __forceinline__ short f2bf(float f) {  // RNE fp32->bf16
  unsigned u = __float_as_uint(f);
  u += 0x7fffu + ((u >> 16) & 1u);
  return (short)(u >> 16);
}
static __device__ __forceinline__ float bf2f(short s) {
  return __uint_as_float(((unsigned)(unsigned short)s) << 16);
}
static __device__ __forceinline__ float fexp2(float x) {  // v_exp_f32 (base-2)
#if __has_builtin(__builtin_amdgcn_exp2f)
  return __builtin_amdgcn_exp2f(x);
#else
  return exp2f(x);
#endif
}
static __device__ __forceinline__ unsigned pack2(float lo, float hi) {
  return (unsigned)(unsigned short)f2bf(lo) | ((unsigned)(unsigned short)f2bf(hi) << 16);
}

// ---------------- K0: W -> WbT (192 x 384) bf16, row n = output col ---------
__global__ __launch_bounds__(256) void wconv_kernel(
    const float* __restrict__ Wq, const float* __restrict__ Wk,
    const float* __restrict__ Wv, short* __restrict__ WbT) {
  int idx = blockIdx.x * 256 + threadIdx.x;  // n*384 + k, 73728 total
  int n = idx / 384, k = idx - n * 384;
  const float* W = (n < 64) ? Wq : (n < 128) ? Wk : Wv;
  WbT[idx] = f2bf(W[k * 64 + (n & 63)]);
}

// ---------------- K1: proj GEMM, 16-row tiles (1024 blocks, 4/CU) -----------
__global__ __launch_bounds__(256) void proj_kernel(
    const float* __restrict__ x, const short* __restrict__ WbT,
    short* __restrict__ qb, short* __restrict__ kb, short* __restrict__ vT) {
  __shared__ short xs[16][392];    // stride 392: banks 2-way (free)
  __shared__ short vtile[64][20];  // v-tile transpose bounce
  const int tid = threadIdx.x;
  const int t0 = blockIdx.x * 16;  // global row (b*2048 + t)
  const float* xb = x + (size_t)t0 * Cn;
  #pragma unroll
  for (int i = 0; i < 6; ++i) {
    int j = tid + i * 256;  // float4 index, 1536 total
    int row = j / 96, colv = (j - row * 96) * 4;
    float4 v = *(const float4*)(xb + row * Cn + colv);
    short4 s4; s4.x = f2bf(v.x); s4.y = f2bf(v.y); s4.z = f2bf(v.z); s4.w = f2bf(v.w);
    *(short4*)(&xs[row][colv]) = s4;
  }
  __syncthreads();
  const int w = tid >> 6, l15 = tid & 15, quad = (tid & 63) >> 4;
  f32x4 acc[3] = {};
  for (int ks = 0; ks < 12; ++ks) {
    bf16x8 a = *(const bf16x8*)(&xs[l15][ks * 32 + quad * 8]);
    #pragma unroll
    for (int cf = 0; cf < 3; ++cf) {
      bf16x8 bfr = *(const bf16x8*)(WbT + (size_t)(48 * w + 16 * cf + l15) * Cn + ks * 32 + quad * 8);
      acc[cf] = MFMA(a, bfr, acc[cf]);
    }
  }
  #pragma unroll
  for (int cf = 0; cf < 3; ++cf) {
    int cbase = 48 * w + 16 * cf, c = cbase + l15;
    #pragma unroll
    for (int r = 0; r < 4; ++r) {
      int row = t0 + quad * 4 + r;
      short val = f2bf(acc[cf][r]);
      if (cbase < 64)       qb[(size_t)row * Hn + c] = val;
      else if (cbase < 128) kb[(size_t)row * Hn + (c - 64)] = val;
      else                  vtile[c - 128][quad * 4 + r] = val;
    }
  }
  __syncthreads();
  const int b = t0 >> 11, t0l = t0 & 2047;
  int h = tid >> 2, tseg = (tid & 3) * 4;
  *(short4*)(vT + ((size_t)(b * Hn + h)) * Tn + t0l + tseg) =
      *(const short4*)(&vtile[h][tseg]);
}

// ---------------- K2: balanced column exp-sums -> pL partials (NO E store) --
// Pair (colchunk j: 32-j t-groups) with (colchunk 31-j: j+1 t-groups) = 33.
// unit = ((b*16 + j)*8 + u): u-th eighth of the pair's 33 t-group list.
// 3-deep A-frag prefetch (A/B/C buffers): 2 chunk-loads in flight per comp.
__global__ __launch_bounds__(256) void colstats_kernel(
    const short* __restrict__ qb, const short* __restrict__ kb,
    float* __restrict__ pL) {
  const int unit = blockIdx.x;
  const int b = unit >> 7, rem = unit & 127;
  const int j = rem >> 3, u = rem & 7;
  const int lo = (u * 33) >> 3, hi = ((u + 1) * 33) >> 3;  // 4 or 5 entries
  const int big = 32 - j;
  const int tid = threadIdx.x, w = tid >> 6, l15 = tid & 15, quad = (tid & 63) >> 4;
  __shared__ float redl[64][17];

  auto run = [&](const int i, const int k0, const int k1, const int slot) {
    const int s0 = i << 6;
    float l[4] = {0.f, 0.f, 0.f, 0.f};
    const int n = k1 - k0;
    if (n > 0) {                           // block-uniform: barrier-safe
      bf16x8 bk[8];
      #pragma unroll
      for (int nf = 0; nf < 4; ++nf) {
        const size_t krow = (size_t)(b * Tn + s0 + 16 * nf + l15) * Hn;
        bk[2 * nf]     = *(const bf16x8*)(kb + krow + quad * 8);
        bk[2 * nf + 1] = *(const bf16x8*)(kb + krow + 32 + quad * 8);
      }
      auto cload = [&](bf16x8& A0, bf16x8& A1, int k) {
        size_t ar = (size_t)(b * Tn + ((i + k) << 6) + 16 * w + l15) * Hn;
        A0 = *(const bf16x8*)(qb + ar + quad * 8);
        A1 = *(const bf16x8*)(qb + ar + 32 + quad * 8);
      };
      auto ccomp = [&](bf16x8 A0, bf16x8 A1, int k) {
        f32x4 sc[4] = {};
        #pragma unroll
        for (int nf = 0; nf < 4; ++nf) {
          sc[nf] = MFMA(A0, bk[2 * nf], sc[nf]);
          sc[nf] = MFMA(A1, bk[2 * nf + 1], sc[nf]);
        }
        const bool diag = (k == 0);
        const int tb = ((i + k) << 6) + 16 * w + quad * 4;
        #pragma unroll
        for (int nf = 0; nf < 4; ++nf) {
          int s = s0 + 16 * nf + l15;
          #pragma unroll
          for (int r = 0; r < 4; ++r) {
            float v = sc[nf][r] * SCALE2;            // exp2-domain score
            if (diag && (tb + r) < s) v = -INFINITY; // exp2(-inf) = 0
            l[nf] += fexp2(v);
          }
        }
      };
      bf16x8 a0A, a1A, a0B, a1B, a0C, a1C;
      cload(a0A, a1A, k0);
      if (n > 1) cload(a0B, a1B, k0 + 1);
      if (n > 2) cload(a0C, a1C, k0 + 2);
      int k = k0;
      while (k + 3 < k1) {  // 3x unrolled steady state, 2 loads in flight
        ccomp(a0A, a1A, k);     cload(a0A, a1A, k + 3);
        ccomp(a0B, a1B, k + 1); if (k + 4 < k1) cload(a0B, a1B, k + 4);
        ccomp(a0C, a1C, k + 2); if (k + 5 < k1) cload(a0C, a1C, k + 5);
        k += 3;
      }
      const int rem2 = k1 - k;
      if (rem2 > 0) ccomp(a0A, a1A, k);
      if (rem2 > 1) ccomp(a0B, a1B, k + 1);
      if (rem2 > 2) ccomp(a0C, a1C, k + 2);
    }
    __syncthreads();  // protect redl reuse across phases
    #pragma unroll
    for (int nf = 0; nf < 4; ++nf) redl[16 * nf + l15][w * 4 + quad] = l[nf];
    __syncthreads();
    if (tid < 64) {
      float ls = 0.f;
      #pragma unroll
      for (int q2 = 0; q2 < 16; ++q2) ls += redl[tid][q2];
      pL[unit * 128 + slot * 64 + tid] = ls;
    }
  };
  run(j, lo, min(hi, big), 0);                       // big member: colchunk j
  run(31 - j, max(lo, big) - big, hi - big, 1);      // small: colchunk 31-j
}

// ---------------- K3: vS[h][s] = vT[h][s] / L[s] ----------------------------
// L[s] = sum over the 8 units of column-chunk s's pair (slot by membership).
__global__ __launch_bounds__(256) void vhat_kernel(
    const short* __restrict__ vT, const float* __restrict__ pL,
    short* __restrict__ vS) {
  int gid = blockIdx.x * 256 + threadIdx.x;  // 131072 threads x 8 elems
  size_t base = (size_t)gid * 8;
  int b = (int)(base >> 17), s = (int)(base & 2047);
  int i = s >> 6, c = s & 63;
  int j2 = (i < 16) ? i : 31 - i;
  int slot = (i < 16) ? 0 : 1;
  const float* pp = pL + (size_t)((b * 16 + j2) * 8) * 128 + slot * 64 + c;
  float L0x = 0.f, L0y = 0.f, L0z = 0.f, L0w = 0.f;
  float L1x = 0.f, L1y = 0.f, L1z = 0.f, L1w = 0.f;
  #pragma unroll
  for (int u = 0; u < 8; ++u) {
    float4 p0 = *(const float4*)(pp + u * 128);
    float4 p1 = *(const float4*)(pp + u * 128 + 4);
    L0x += p0.x; L0y += p0.y; L0z += p0.z; L0w += p0.w;
    L1x += p1.x; L1y += p1.y; L1z += p1.z; L1w += p1.w;
  }
  short4 v0 = *(const short4*)(vT + base);
  short4 v1 = *(const short4*)(vT + base + 4);
  short4 r0, r1;
  r0.x = f2bf(bf2f(v0.x) / L0x); r0.y = f2bf(bf2f(v0.y) / L0y);
  r0.z = f2bf(bf2f(v0.z) / L0z); r0.w = f2bf(bf2f(v0.w) / L0w);
  r1.x = f2bf(bf2f(v1.x) / L1x); r1.y = f2bf(bf2f(v1.y) / L1y);
  r1.z = f2bf(bf2f(v1.z) / L1z); r1.w = f2bf(bf2f(v1.w) / L1w);
  *(short4*)(vS + base) = r0;
  *(short4*)(vS + base + 4) = r1;
}

// ---------------- K4: FUSED out = exp(QK^T)_tri . vS^T, atomic-free ---------
// Block = (b, tile, 16-row strip); 1024 blocks, heavy tiles first.
// The tile's (tile+1) s-chunks are split across the block's 4 waves (stride 4);
// per-wave partial acc is reduced via LDS, then ONE coalesced f32 store per
// out element (no atomics, no pre-zero of out).
// Per chunk per wave: 8 MFMA S^T=K.Q (lane&15 = t), mask+exp2, bf16-pack,
// per-wave XOR-swizzled LDS transpose (no barriers), 8 MFMA PV.
// kf and vf are prefetched one owned-chunk ahead (single-buffered: loads issue
// after the MFMAs that consume the previous contents).
__global__ __launch_bounds__(256, 3) void outg_kernel(
    const short* __restrict__ qb, const short* __restrict__ kb,
    const short* __restrict__ vS, float* __restrict__ out) {
  const int bid = blockIdx.x;
  const int tile = 31 - (bid >> 5);        // heavy (many-chunk) tiles first
  const int sub = bid & 31;
  const int b = sub >> 2, strip = sub & 3;
  const int nch = tile + 1;
  const int tid = threadIdx.x, w = tid >> 6, l15 = tid & 15, quad = (tid & 63) >> 4;
  __shared__ unsigned plds[4][512];        // per-wave 2KB P tile [16 t][64 s] bf16
  __shared__ float red[4][16][64];         // cross-wave accumulator reduce
  // XOR swizzle: byte ^= (l15&7)<<4 breaks the 128B-row same-bank pattern.
  const int swz = (l15 & 7) << 4;
  int wroff[8];                            // u32 offsets: s = 16nf+4q+{2p,2p+1}
  #pragma unroll
  for (int nf = 0; nf < 4; ++nf)
    #pragma unroll
    for (int p = 0; p < 2; ++p)
      wroff[2 * nf + p] = (l15 * 128 + ((nf * 32 + quad * 8 + p * 4) ^ swz)) >> 2;
  const int rd0 = (l15 * 128 + ((quad * 16) ^ swz)) >> 2;        // s = 8q..8q+7
  const int rd1 = (l15 * 128 + ((64 + quad * 16) ^ swz)) >> 2;   // s = 32+8q..+7
  const size_t QKbase = (size_t)b * Tn * Hn;
  const size_t Vbase  = (size_t)b * Hn * Tn;
  const int tbase = (tile << 6) + 16 * strip;   // this block's 16 output rows
  const int tg = tbase + l15;                   // this lane's query row t

  const size_t qrow = QKbase + (size_t)(tbase + l15) * Hn;
  const bf16x8 qf0 = *(const bf16x8*)(qb + qrow + quad * 8);     // B[n=t][k=h]
  const bf16x8 qf1 = *(const bf16x8*)(qb + qrow + 32 + quad * 8);

  f32x4 acc[4] = {};
  bf16x8 kf[8], vf[8];
  auto loadK = [&](int ch) {               // A[m=s][k=h] frags for S^T
    const int s0 = ch << 6;
    #pragma unroll
    for (int nf = 0; nf < 4; ++nf) {
      const size_t kr = QKbase + (size_t)(s0 + 16 * nf + l15) * Hn;
      kf[2 * nf]     = *(const bf16x8*)(kb + kr + quad * 8);
      kf[2 * nf + 1] = *(const bf16x8*)(kb + kr + 32 + quad * 8);
    }
  };
  auto loadV = [&](int ch) {               // B[n=h][k=s] frags for PV
    const int s0 = ch << 6;
    #pragma unroll
    for (int nf = 0; nf < 4; ++nf) {
      const size_t vr = Vbase + (size_t)(16 * nf + l15) * Tn + s0;
      vf[2 * nf]     = *(const bf16x8*)(vS + vr + quad * 8);
      vf[2 * nf + 1] = *(const bf16x8*)(vS + vr + 32 + quad * 8);
    }
  };

  if (w < nch) { loadK(w); loadV(w); }     // this wave's first owned chunk
  for (int ch = w; ch < nch; ch += 4) {
    const int s0 = ch << 6;
    f32x4 sc[4] = {};                      // D[s][t]: lane&15 = t, s = 16nf+4q+r
    #pragma unroll
    for (int nf = 0; nf < 4; ++nf) {
      sc[nf] = MFMA(kf[2 * nf], qf0, sc[nf]);
      sc[nf] = MFMA(kf[2 * nf + 1], qf1, sc[nf]);
    }
    const int nx = ch + 4;
    if (nx < nch) loadK(nx);               // prefetch next owned chunk (WAR ok)
    const bool diag = (ch == tile);
    #pragma unroll
    for (int nf = 0; nf < 4; ++nf) {
      float ev[4];
      #pragma unroll
      for (int r = 0; r < 4; ++r) {
        float v = sc[nf][r] * SCALE2;
        const int s = s0 + 16 * nf + quad * 4 + r;
        if (diag && tg < s) v = -INFINITY;           // causal: exp2(-inf)=0
        ev[r] = fexp2(v);
      }
      plds[w][wroff[2 * nf]]     = pack2(ev[0], ev[1]);
      plds[w][wroff[2 * nf + 1]] = pack2(ev[2], ev[3]);
    }
    __asm__ __volatile__("" ::: "memory");  // order LDS write->read
    const bf16x8 a0 = __builtin_bit_cast(bf16x8, *(const u32x4*)(&plds[w][rd0]));
    const bf16x8 a1 = __builtin_bit_cast(bf16x8, *(const u32x4*)(&plds[w][rd1]));
    #pragma unroll
    for (int nf = 0; nf < 4; ++nf) {       // D[t][h]: lane&15 = h, t = 4q+r
      acc[nf] = MFMA(a0, vf[2 * nf], acc[nf]);
      acc[nf] = MFMA(a1, vf[2 * nf + 1], acc[nf]);
    }
    if (nx < nch) loadV(nx);               // prefetch next owned chunk (WAR ok)
  }

  // cross-wave reduction of the 4 partial accumulators, then one plain store
  #pragma unroll
  for (int nf = 0; nf < 4; ++nf)
    #pragma unroll
    for (int r = 0; r < 4; ++r)
      red[w][quad * 4 + r][16 * nf + l15] = acc[nf][r];
  __syncthreads();
  {
    const int row = tid >> 4, c4 = (tid & 15) * 4;
    float4 s0 = *(const float4*)(&red[0][row][c4]);
    float4 s1 = *(const float4*)(&red[1][row][c4]);
    float4 s2 = *(const float4*)(&red[2][row][c4]);
    float4 s3 = *(const float4*)(&red[3][row][c4]);
    float4 t;
    t.x = (s0.x + s1.x) + (s2.x + s3.x);
    t.y = (s0.y + s1.y) + (s2.y + s3.y);
    t.z = (s0.z + s1.z) + (s2.z + s3.z);
    t.w = (s0.w + s1.w) + (s2.w + s3.w);
    *(float4*)(&out[QKbase + (size_t)(tbase + row) * Hn + c4]) = t;
  }
}

extern "C" void kernel_launch(void* const* d_in, const int* in_sizes, int n_in,
                              void* d_out, int out_size, void* d_ws, size_t ws_size,
                              hipStream_t stream) {
  const float* x  = (const float*)d_in[0];
  const float* Wq = (const float*)d_in[1];
  const float* Wk = (const float*)d_in[2];
  const float* Wv = (const float*)d_in[3];
  char* ws = (char*)d_ws;                          // needs ~9.1 MB
  short* qb   = (short*)(ws);                      // 2 MB (T,H)
  short* kb   = (short*)(ws + 2097152);            // 2 MB (T,H)
  short* vT   = (short*)(ws + 4194304);            // 2 MB (H,T)
  short* vS   = (short*)(ws + 6291456);            // 2 MB (H,T) v/L
  short* WbT  = (short*)(ws + 8388608);            // 144 KB
  float* pL   = (float*)(ws + 8536064);            // 512 KB unit partial sums
  float* outp = (float*)d_out;

  hipLaunchKernelGGL(wconv_kernel, dim3(288), dim3(256), 0, stream, Wq, Wk, Wv, WbT);
  hipLaunchKernelGGL(proj_kernel, dim3(Bn * Tn / 16), dim3(256), 0, stream, x, WbT, qb, kb, vT);
  hipLaunchKernelGGL(colstats_kernel, dim3(1024), dim3(256), 0, stream, qb, kb, pL);
  hipLaunchKernelGGL(vhat_kernel, dim3(512), dim3(256), 0, stream, vT, pL, vS);
  hipLaunchKernelGGL(outg_kernel, dim3(1024), dim3(256), 0, stream, qb, kb, vS, outp);
}

// Round 3
// 137.537 us; speedup vs baseline: 1.1817x; 1.0724x over previous
//
#include <hip/hip_runtime.h>
#include <hip/hip_bf16.h>
#include <math.h>

#define Bn 8
#define Tn 2048
#define Cn 384
#define Hn 64
#define SCALE2 0.07362241f            // 384^-0.5 * log2(e): exp(x*scale) = 2^(x*SCALE2)

using bf16x8 = __attribute__((ext_vector_type(8))) short;  // 8 bf16 = 4 VGPRs
using f32x4  = __attribute__((ext_vector_type(4))) float;
using u32x4  = __attribute__((ext_vector_type(4))) unsigned;

#define MFMA(a, b, c) __builtin_amdgcn_mfma_f32_16x16x32_bf16((a), (b), (c), 0, 0, 0)

static __device__ __forceinline__ short f2bf(float f) {  // RNE fp32->bf16
  unsigned u = __float_as_uint(f);
  u += 0x7fffu + ((u >> 16) & 1u);
  return (short)(u >> 16);
}
static __device__ __forceinline__ float bf2f(short s) {
  return __uint_as_float(((unsigned)(unsigned short)s) << 16);
}
static __device__ __forceinline__ float fexp2(float x) {  // v_exp_f32 (base-2)
#if __has_builtin(__builtin_amdgcn_exp2f)
  return __builtin_amdgcn_exp2f(x);
#else
  return exp2f(x);
#endif
}
static __device__ __forceinline__ unsigned pack2(float lo, float hi) {
  return (unsigned)(unsigned short)f2bf(lo) | ((unsigned)(unsigned short)f2bf(hi) << 16);
}
// Typed (TBAA-safe) LDS 16B gather: 4 x u32 loads, compiler merges to b128.
static __device__ __forceinline__ bf16x8 ldp(const unsigned* p) {
  u32x4 t; t[0] = p[0]; t[1] = p[1]; t[2] = p[2]; t[3] = p[3];
  return __builtin_bit_cast(bf16x8, t);
}

// ---------------- K0: W -> WbT (192 x 384) bf16, row n = output col ---------
__global__ __launch_bounds__(256) void wconv_kernel(
    const float* __restrict__ Wq, const float* __restrict__ Wk,
    const float* __restrict__ Wv, short* __restrict__ WbT) {
  int idx = blockIdx.x * 256 + threadIdx.x;  // n*384 + k, 73728 total
  int n = idx / 384, k = idx - n * 384;
  const float* W = (n < 64) ? Wq : (n < 128) ? Wk : Wv;
  WbT[idx] = f2bf(W[k * 64 + (n & 63)]);
}

// ---------------- K1: proj GEMM, 16-row tiles (1024 blocks, 4/CU) -----------
__global__ __launch_bounds__(256) void proj_kernel(
    const float* __restrict__ x, const short* __restrict__ WbT,
    short* __restrict__ qb, short* __restrict__ kb, short* __restrict__ vT) {
  __shared__ short xs[16][392];    // stride 392: banks 2-way (free)
  __shared__ short vtile[64][20];  // v-tile transpose bounce
  const int tid = threadIdx.x;
  const int t0 = blockIdx.x * 16;  // global row (b*2048 + t)
  const float* xb = x + (size_t)t0 * Cn;
  #pragma unroll
  for (int i = 0; i < 6; ++i) {
    int j = tid + i * 256;  // float4 index, 1536 total
    int row = j / 96, colv = (j - row * 96) * 4;
    float4 v = *(const float4*)(xb + row * Cn + colv);
    short4 s4; s4.x = f2bf(v.x); s4.y = f2bf(v.y); s4.z = f2bf(v.z); s4.w = f2bf(v.w);
    *(short4*)(&xs[row][colv]) = s4;
  }
  __syncthreads();
  const int w = tid >> 6, l15 = tid & 15, quad = (tid & 63) >> 4;
  f32x4 acc[3] = {};
  for (int ks = 0; ks < 12; ++ks) {
    bf16x8 a = *(const bf16x8*)(&xs[l15][ks * 32 + quad * 8]);
    #pragma unroll
    for (int cf = 0; cf < 3; ++cf) {
      bf16x8 bfr = *(const bf16x8*)(WbT + (size_t)(48 * w + 16 * cf + l15) * Cn + ks * 32 + quad * 8);
      acc[cf] = MFMA(a, bfr, acc[cf]);
    }
  }
  #pragma unroll
  for (int cf = 0; cf < 3; ++cf) {
    int cbase = 48 * w + 16 * cf, c = cbase + l15;
    #pragma unroll
    for (int r = 0; r < 4; ++r) {
      int row = t0 + quad * 4 + r;
      short val = f2bf(acc[cf][r]);
      if (cbase < 64)       qb[(size_t)row * Hn + c] = val;
      else if (cbase < 128) kb[(size_t)row * Hn + (c - 64)] = val;
      else                  vtile[c - 128][quad * 4 + r] = val;
    }
  }
  __syncthreads();
  const int b = t0 >> 11, t0l = t0 & 2047;
  int h = tid >> 2, tseg = (tid & 3) * 4;
  *(short4*)(vT + ((size_t)(b * Hn + h)) * Tn + t0l + tseg) =
      *(const short4*)(&vtile[h][tseg]);
}

// ---------------- K2: balanced column exp-sums -> pL partials (NO E store) --
// Pair (colchunk j: 32-j t-groups) with (colchunk 31-j: j+1 t-groups) = 33.
// unit = ((b*16 + j)*8 + u): u-th eighth of the pair's 33 t-group list.
// 3-deep A-frag prefetch (A/B/C buffers): 2 chunk-loads in flight per comp.
__global__ __launch_bounds__(256) void colstats_kernel(
    const short* __restrict__ qb, const short* __restrict__ kb,
    float* __restrict__ pL) {
  const int unit = blockIdx.x;
  const int b = unit >> 7, rem = unit & 127;
  const int j = rem >> 3, u = rem & 7;
  const int lo = (u * 33) >> 3, hi = ((u + 1) * 33) >> 3;  // 4 or 5 entries
  const int big = 32 - j;
  const int tid = threadIdx.x, w = tid >> 6, l15 = tid & 15, quad = (tid & 63) >> 4;
  __shared__ float redl[64][17];

  auto run = [&](const int i, const int k0, const int k1, const int slot) {
    const int s0 = i << 6;
    float l[4] = {0.f, 0.f, 0.f, 0.f};
    const int n = k1 - k0;
    if (n > 0) {                           // block-uniform: barrier-safe
      bf16x8 bk[8];
      #pragma unroll
      for (int nf = 0; nf < 4; ++nf) {
        const size_t krow = (size_t)(b * Tn + s0 + 16 * nf + l15) * Hn;
        bk[2 * nf]     = *(const bf16x8*)(kb + krow + quad * 8);
        bk[2 * nf + 1] = *(const bf16x8*)(kb + krow + 32 + quad * 8);
      }
      auto cload = [&](bf16x8& A0, bf16x8& A1, int k) {
        size_t ar = (size_t)(b * Tn + ((i + k) << 6) + 16 * w + l15) * Hn;
        A0 = *(const bf16x8*)(qb + ar + quad * 8);
        A1 = *(const bf16x8*)(qb + ar + 32 + quad * 8);
      };
      auto ccomp = [&](bf16x8 A0, bf16x8 A1, int k) {
        f32x4 sc[4] = {};
        #pragma unroll
        for (int nf = 0; nf < 4; ++nf) {
          sc[nf] = MFMA(A0, bk[2 * nf], sc[nf]);
          sc[nf] = MFMA(A1, bk[2 * nf + 1], sc[nf]);
        }
        const bool diag = (k == 0);
        const int tb = ((i + k) << 6) + 16 * w + quad * 4;
        #pragma unroll
        for (int nf = 0; nf < 4; ++nf) {
          int s = s0 + 16 * nf + l15;
          #pragma unroll
          for (int r = 0; r < 4; ++r) {
            float v = sc[nf][r] * SCALE2;            // exp2-domain score
            if (diag && (tb + r) < s) v = -INFINITY; // exp2(-inf) = 0
            l[nf] += fexp2(v);
          }
        }
      };
      bf16x8 a0A, a1A, a0B, a1B, a0C, a1C;
      cload(a0A, a1A, k0);
      if (n > 1) cload(a0B, a1B, k0 + 1);
      if (n > 2) cload(a0C, a1C, k0 + 2);
      int k = k0;
      while (k + 3 < k1) {  // 3x unrolled steady state, 2 loads in flight
        ccomp(a0A, a1A, k);     cload(a0A, a1A, k + 3);
        ccomp(a0B, a1B, k + 1); if (k + 4 < k1) cload(a0B, a1B, k + 4);
        ccomp(a0C, a1C, k + 2); if (k + 5 < k1) cload(a0C, a1C, k + 5);
        k += 3;
      }
      const int rem2 = k1 - k;
      if (rem2 > 0) ccomp(a0A, a1A, k);
      if (rem2 > 1) ccomp(a0B, a1B, k + 1);
      if (rem2 > 2) ccomp(a0C, a1C, k + 2);
    }
    __syncthreads();  // protect redl reuse across phases
    #pragma unroll
    for (int nf = 0; nf < 4; ++nf) redl[16 * nf + l15][w * 4 + quad] = l[nf];
    __syncthreads();
    if (tid < 64) {
      float ls = 0.f;
      #pragma unroll
      for (int q2 = 0; q2 < 16; ++q2) ls += redl[tid][q2];
      pL[unit * 128 + slot * 64 + tid] = ls;
    }
  };
  run(j, lo, min(hi, big), 0);                       // big member: colchunk j
  run(31 - j, max(lo, big) - big, hi - big, 1);      // small: colchunk 31-j
}

// ---------------- K3: vS[h][s] = vT[h][s] / L[s] ----------------------------
// L[s] = sum over the 8 units of column-chunk s's pair (slot by membership).
__global__ __launch_bounds__(256) void vhat_kernel(
    const short* __restrict__ vT, const float* __restrict__ pL,
    short* __restrict__ vS) {
  int gid = blockIdx.x * 256 + threadIdx.x;  // 131072 threads x 8 elems
  size_t base = (size_t)gid * 8;
  int b = (int)(base >> 17), s = (int)(base & 2047);
  int i = s >> 6, c = s & 63;
  int j2 = (i < 16) ? i : 31 - i;
  int slot = (i < 16) ? 0 : 1;
  const float* pp = pL + (size_t)((b * 16 + j2) * 8) * 128 + slot * 64 + c;
  float L0x = 0.f, L0y = 0.f, L0z = 0.f, L0w = 0.f;
  float L1x = 0.f, L1y = 0.f, L1z = 0.f, L1w = 0.f;
  #pragma unroll
  for (int u = 0; u < 8; ++u) {
    float4 p0 = *(const float4*)(pp + u * 128);
    float4 p1 = *(const float4*)(pp + u * 128 + 4);
    L0x += p0.x; L0y += p0.y; L0z += p0.z; L0w += p0.w;
    L1x += p1.x; L1y += p1.y; L1z += p1.z; L1w += p1.w;
  }
  short4 v0 = *(const short4*)(vT + base);
  short4 v1 = *(const short4*)(vT + base + 4);
  short4 r0, r1;
  r0.x = f2bf(bf2f(v0.x) / L0x); r0.y = f2bf(bf2f(v0.y) / L0y);
  r0.z = f2bf(bf2f(v0.z) / L0z); r0.w = f2bf(bf2f(v0.w) / L0w);
  r1.x = f2bf(bf2f(v1.x) / L1x); r1.y = f2bf(bf2f(v1.y) / L1y);
  r1.z = f2bf(bf2f(v1.z) / L1z); r1.w = f2bf(bf2f(v1.w) / L1w);
  *(short4*)(vS + base) = r0;
  *(short4*)(vS + base + 4) = r1;
}

// ---------------- K4: FUSED out = exp(QK^T)_tri . vS^T, atomic-free ---------
// Block = (b, tile, half): 32 output rows (2 strips of 16), 512 blocks, 2/CU,
// heavy tiles first. The tile's nch chunks split across 4 waves (stride 4);
// each wave reuses its kf/vf for BOTH strips (halves K/V L2 traffic vs r2).
// Per chunk per wave: 16 MFMA S^T=K.Q (2 strips), mask+exp2, bf16-pack,
// per-wave XOR-swizzled LDS transpose (no barriers, typed u32 accesses — no
// blunt memory clobber, so vmcnt prefetches stay in flight), 16 MFMA PV.
// Cross-wave partials reduced via LDS, one coalesced f32 store per element.
__global__ __launch_bounds__(256, 2) void outg_kernel(
    const short* __restrict__ qb, const short* __restrict__ kb,
    const short* __restrict__ vS, float* __restrict__ out) {
  const int bid = blockIdx.x;
  const int tile = 31 - (bid >> 4);        // heavy (many-chunk) tiles first
  const int sub = bid & 15;
  const int b = sub >> 1, half = sub & 1;
  const int nch = tile + 1;
  const int tid = threadIdx.x, w = tid >> 6, l15 = tid & 15, quad = (tid & 63) >> 4;
  __shared__ unsigned plds[4][512];        // per-wave 2KB P tile [16 t][64 s] bf16
  __shared__ float red[4][32][64];         // cross-wave accumulator reduce
  // XOR swizzle: byte ^= (l15&7)<<4 breaks the 128B-row same-bank pattern.
  const int swz = (l15 & 7) << 4;
  int wroff[8];                            // u32 offsets: s = 16nf+4q+{2p,2p+1}
  #pragma unroll
  for (int nf = 0; nf < 4; ++nf)
    #pragma unroll
    for (int p = 0; p < 2; ++p)
      wroff[2 * nf + p] = (l15 * 128 + ((nf * 32 + quad * 8 + p * 4) ^ swz)) >> 2;
  const int rd0 = (l15 * 128 + ((quad * 16) ^ swz)) >> 2;        // s = 8q..8q+7
  const int rd1 = (l15 * 128 + ((64 + quad * 16) ^ swz)) >> 2;   // s = 32+8q..+7
  const size_t QKbase = (size_t)b * Tn * Hn;
  const size_t Vbase  = (size_t)b * Hn * Tn;
  const int tbase = (tile << 6) + (half << 5);  // this block's 32 output rows
  const int tg0 = tbase + l15;                  // strip0 lane query row
  const int tg1 = tbase + 16 + l15;             // strip1 lane query row

  const size_t qrow0 = QKbase + (size_t)(tbase + l15) * Hn;
  const size_t qrow1 = qrow0 + 16 * Hn;
  const bf16x8 qf00 = *(const bf16x8*)(qb + qrow0 + quad * 8);   // B[n=t][k=h]
  const bf16x8 qf01 = *(const bf16x8*)(qb + qrow0 + 32 + quad * 8);
  const bf16x8 qf10 = *(const bf16x8*)(qb + qrow1 + quad * 8);
  const bf16x8 qf11 = *(const bf16x8*)(qb + qrow1 + 32 + quad * 8);

  f32x4 acc0[4] = {}, acc1[4] = {};
  bf16x8 kf[8], vf[8];
  auto loadK = [&](int ch) {               // A[m=s][k=h] frags for S^T
    const int s0 = ch << 6;
    #pragma unroll
    for (int nf = 0; nf < 4; ++nf) {
      const size_t kr = QKbase + (size_t)(s0 + 16 * nf + l15) * Hn;
      kf[2 * nf]     = *(const bf16x8*)(kb + kr + quad * 8);
      kf[2 * nf + 1] = *(const bf16x8*)(kb + kr + 32 + quad * 8);
    }
  };
  auto loadV = [&](int ch) {               // B[n=h][k=s] frags for PV
    const int s0 = ch << 6;
    #pragma unroll
    for (int nf = 0; nf < 4; ++nf) {
      const size_t vr = Vbase + (size_t)(16 * nf + l15) * Tn + s0;
      vf[2 * nf]     = *(const bf16x8*)(vS + vr + quad * 8);
      vf[2 * nf + 1] = *(const bf16x8*)(vS + vr + 32 + quad * 8);
    }
  };
  // strip = {exp+pack -> LDS -> read back A-frags -> 8 PV MFMA into acc}
  auto strip = [&](const f32x4 (&sc)[4], int s0, bool diag, int tg, f32x4 (&acc)[4]) {
    #pragma unroll
    for (int nf = 0; nf < 4; ++nf) {
      float ev[4];
      #pragma unroll
      for (int r = 0; r < 4; ++r) {
        float v = sc[nf][r] * SCALE2;
        const int s = s0 + 16 * nf + quad * 4 + r;
        if (diag && tg < s) v = -INFINITY;           // causal: exp2(-inf)=0
        ev[r] = fexp2(v);
      }
      plds[w][wroff[2 * nf]]     = pack2(ev[0], ev[1]);
      plds[w][wroff[2 * nf + 1]] = pack2(ev[2], ev[3]);
    }
    // typed u32 reads: may-alias with the stores above -> compiler keeps
    // order; DS pipe is in-order per wave -> data correct, no vmcnt drain.
    const bf16x8 a0 = ldp(&plds[w][rd0]);
    const bf16x8 a1 = ldp(&plds[w][rd1]);
    __builtin_amdgcn_s_setprio(1);
    #pragma unroll
    for (int nf = 0; nf < 4; ++nf) {       // D[t][h]: lane&15 = h, t = 4q+r
      acc[nf] = MFMA(a0, vf[2 * nf], acc[nf]);
      acc[nf] = MFMA(a1, vf[2 * nf + 1], acc[nf]);
    }
    __builtin_amdgcn_s_setprio(0);
  };

  if (w < nch) { loadK(w); loadV(w); }     // this wave's first owned chunk
  for (int ch = w; ch < nch; ch += 4) {
    const int s0 = ch << 6;
    f32x4 sc0[4] = {}, sc1[4] = {};        // D[s][t]: lane&15 = t, s = 16nf+4q+r
    __builtin_amdgcn_s_setprio(1);
    #pragma unroll
    for (int nf = 0; nf < 4; ++nf) {
      sc0[nf] = MFMA(kf[2 * nf], qf00, sc0[nf]);
      sc0[nf] = MFMA(kf[2 * nf + 1], qf01, sc0[nf]);
    }
    #pragma unroll
    for (int nf = 0; nf < 4; ++nf) {
      sc1[nf] = MFMA(kf[2 * nf], qf10, sc1[nf]);
      sc1[nf] = MFMA(kf[2 * nf + 1], qf11, sc1[nf]);
    }
    __builtin_amdgcn_s_setprio(0);
    const int nx = ch + 4;
    if (nx < nch) loadK(nx);               // prefetch next owned chunk (WAR ok)
    const bool diag = (ch == tile);
    strip(sc0, s0, diag, tg0, acc0);       // strip0: exp->LDS->PV
    strip(sc1, s0, diag, tg1, acc1);       // strip1 reuses same LDS region
    if (nx < nch) loadV(nx);               // prefetch next owned chunk (WAR ok)
  }

  // cross-wave reduction of the 4 partial accumulators, then one plain store
  #pragma unroll
  for (int nf = 0; nf < 4; ++nf)
    #pragma unroll
    for (int r = 0; r < 4; ++r) {
      red[w][quad * 4 + r][16 * nf + l15]      = acc0[nf][r];
      red[w][16 + quad * 4 + r][16 * nf + l15] = acc1[nf][r];
    }
  __syncthreads();
  {
    const int row = tid >> 3, c8 = (tid & 7) * 8;   // 32 rows x 8 lanes x 8 cols
    float4 t0 = {0.f, 0.f, 0.f, 0.f}, t1 = {0.f, 0.f, 0.f, 0.f};
    #pragma unroll
    for (int ww = 0; ww < 4; ++ww) {
      float4 s0 = *(const float4*)(&red[ww][row][c8]);
      float4 s1 = *(const float4*)(&red[ww][row][c8 + 4]);
      t0.x += s0.x; t0.y += s0.y; t0.z += s0.z; t0.w += s0.w;
      t1.x += s1.x; t1.y += s1.y; t1.z += s1.z; t1.w += s1.w;
    }
    float* o = &out[QKbase + (size_t)(tbase + row) * Hn + c8];
    *(float4*)(o) = t0;
    *(float4*)(o + 4) = t1;
  }
}

extern "C" void kernel_launch(void* const* d_in, const int* in_sizes, int n_in,
                              void* d_out, int out_size, void* d_ws, size_t ws_size,
                              hipStream_t stream) {
  const float* x  = (const float*)d_in[0];
  const float* Wq = (const float*)d_in[1];
  const float* Wk = (const float*)d_in[2];
  const float* Wv = (const float*)d_in[3];
  char* ws = (char*)d_ws;                          // needs ~9.1 MB
  short* qb   = (short*)(ws);                      // 2 MB (T,H)
  short* kb   = (short*)(ws + 2097152);            // 2 MB (T,H)
  short* vT   = (short*)(ws + 4194304);            // 2 MB (H,T)
  short* vS   = (short*)(ws + 6291456);            // 2 MB (H,T) v/L
  short* WbT  = (short*)(ws + 8388608);            // 144 KB
  float* pL   = (float*)(ws + 8536064);            // 512 KB unit partial sums
  float* outp = (float*)d_out;

  hipLaunchKernelGGL(wconv_kernel, dim3(288), dim3(256), 0, stream, Wq, Wk, Wv, WbT);
  hipLaunchKernelGGL(proj_kernel, dim3(Bn * Tn / 16), dim3(256), 0, stream, x, WbT, qb, kb, vT);
  hipLaunchKernelGGL(colstats_kernel, dim3(1024), dim3(256), 0, stream, qb, kb, pL);
  hipLaunchKernelGGL(vhat_kernel, dim3(512), dim3(256), 0, stream, vT, pL, vS);
  hipLaunchKernelGGL(outg_kernel, dim3(512), dim3(256), 0, stream, qb, kb, vS, outp);
}

// Round 4
// 131.974 us; speedup vs baseline: 1.2316x; 1.0422x over previous
//
#include <hip/hip_runtime.h>
#include <hip/hip_bf16.h>
#include <math.h>

#define Bn 8
#define Tn 2048
#define Cn 384
#define Hn 64
#define SCALE2 0.07362241f            // 384^-0.5 * log2(e): exp(x*scale) = 2^(x*SCALE2)

using bf16x8 = __attribute__((ext_vector_type(8))) short;  // 8 bf16 = 4 VGPRs
using f32x4  = __attribute__((ext_vector_type(4))) float;
using u32x4  = __attribute__((ext_vector_type(4))) unsigned;

#define MFMA(a, b, c) __builtin_amdgcn_mfma_f32_16x16x32_bf16((a), (b), (c), 0, 0, 0)

static __device__ __forceinline__ short f2bf(float f) {  // RNE fp32->bf16
  unsigned u = __float_as_uint(f);
  u += 0x7fffu + ((u >> 16) & 1u);
  return (short)(u >> 16);
}
static __device__ __forceinline__ float bf2f(short s) {
  return __uint_as_float(((unsigned)(unsigned short)s) << 16);
}
static __device__ __forceinline__ float fexp2(float x) {  // v_exp_f32 (base-2)
#if __has_builtin(__builtin_amdgcn_exp2f)
  return __builtin_amdgcn_exp2f(x);
#else
  return exp2f(x);
#endif
}
static __device__ __forceinline__ float frcp(float x) {   // v_rcp_f32 (~1ulp)
#if __has_builtin(__builtin_amdgcn_rcpf)
  return __builtin_amdgcn_rcpf(x);
#else
  return 1.0f / x;
#endif
}
static __device__ __forceinline__ unsigned pack2(float lo, float hi) {
  return (unsigned)(unsigned short)f2bf(lo) | ((unsigned)(unsigned short)f2bf(hi) << 16);
}
// Typed (TBAA-safe) LDS 16B gather: 4 x u32 loads, compiler merges to b128.
static __device__ __forceinline__ bf16x8 ldp(const unsigned* p) {
  u32x4 t; t[0] = p[0]; t[1] = p[1]; t[2] = p[2]; t[3] = p[3];
  return __builtin_bit_cast(bf16x8, t);
}

// ---------------- K0: W -> WbT (192 x 384) bf16 + zero L[b][s] --------------
__global__ __launch_bounds__(256) void wconv_kernel(
    const float* __restrict__ Wq, const float* __restrict__ Wk,
    const float* __restrict__ Wv, short* __restrict__ WbT,
    float* __restrict__ Lsum) {
  int idx = blockIdx.x * 256 + threadIdx.x;  // n*384 + k, 73728 total
  if (idx < Bn * Tn) Lsum[idx] = 0.f;        // 16384 floats, pre-colstats
  int n = idx / 384, k = idx - n * 384;
  const float* W = (n < 64) ? Wq : (n < 128) ? Wk : Wv;
  WbT[idx] = f2bf(W[k * 64 + (n & 63)]);
}

// ---------------- K1: proj GEMM, 16-row tiles (1024 blocks, 4/CU) -----------
__global__ __launch_bounds__(256) void proj_kernel(
    const float* __restrict__ x, const short* __restrict__ WbT,
    short* __restrict__ qb, short* __restrict__ kb, short* __restrict__ vT) {
  __shared__ short xs[16][392];    // stride 392: banks 2-way (free)
  __shared__ short vtile[64][20];  // v-tile transpose bounce
  const int tid = threadIdx.x;
  const int t0 = blockIdx.x * 16;  // global row (b*2048 + t)
  const float* xb = x + (size_t)t0 * Cn;
  #pragma unroll
  for (int i = 0; i < 6; ++i) {
    int j = tid + i * 256;  // float4 index, 1536 total
    int row = j / 96, colv = (j - row * 96) * 4;
    float4 v = *(const float4*)(xb + row * Cn + colv);
    short4 s4; s4.x = f2bf(v.x); s4.y = f2bf(v.y); s4.z = f2bf(v.z); s4.w = f2bf(v.w);
    *(short4*)(&xs[row][colv]) = s4;
  }
  __syncthreads();
  const int w = tid >> 6, l15 = tid & 15, quad = (tid & 63) >> 4;
  f32x4 acc[3] = {};
  for (int ks = 0; ks < 12; ++ks) {
    bf16x8 a = *(const bf16x8*)(&xs[l15][ks * 32 + quad * 8]);
    #pragma unroll
    for (int cf = 0; cf < 3; ++cf) {
      bf16x8 bfr = *(const bf16x8*)(WbT + (size_t)(48 * w + 16 * cf + l15) * Cn + ks * 32 + quad * 8);
      acc[cf] = MFMA(a, bfr, acc[cf]);
    }
  }
  #pragma unroll
  for (int cf = 0; cf < 3; ++cf) {
    int cbase = 48 * w + 16 * cf, c = cbase + l15;
    #pragma unroll
    for (int r = 0; r < 4; ++r) {
      int row = t0 + quad * 4 + r;
      short val = f2bf(acc[cf][r]);
      if (cbase < 64)       qb[(size_t)row * Hn + c] = val;
      else if (cbase < 128) kb[(size_t)row * Hn + (c - 64)] = val;
      else                  vtile[c - 128][quad * 4 + r] = val;
    }
  }
  __syncthreads();
  const int b = t0 >> 11, t0l = t0 & 2047;
  int h = tid >> 2, tseg = (tid & 3) * 4;
  *(short4*)(vT + ((size_t)(b * Hn + h)) * Tn + t0l + tseg) =
      *(const short4*)(&vtile[h][tseg]);
}

// ---------------- K2: balanced column exp-sums -> atomicAdd L[b][s] ---------
// Pair (colchunk j: 32-j t-groups) with (colchunk 31-j: j+1 t-groups) = 33.
// XCD-locked: b = blockIdx&7, so each XCD's L2 holds ONE batch's qb/kb.
// 3-deep A-frag prefetch (A/B/C buffers): 2 chunk-loads in flight per comp.
__global__ __launch_bounds__(256) void colstats_kernel(
    const short* __restrict__ qb, const short* __restrict__ kb,
    float* __restrict__ Lsum) {
  const int unit = ((blockIdx.x & 7) << 7) | (blockIdx.x >> 3);  // b = bid&7
  const int b = unit >> 7, rem = unit & 127;
  const int j = rem >> 3, u = rem & 7;
  const int lo = (u * 33) >> 3, hi = ((u + 1) * 33) >> 3;  // 4 or 5 entries
  const int big = 32 - j;
  const int tid = threadIdx.x, w = tid >> 6, l15 = tid & 15, quad = (tid & 63) >> 4;
  __shared__ float redl[64][17];

  auto run = [&](const int i, const int k0, const int k1) {
    const int s0 = i << 6;
    float l[4] = {0.f, 0.f, 0.f, 0.f};
    const int n = k1 - k0;
    if (n > 0) {                           // block-uniform: barrier-safe
      bf16x8 bk[8];
      #pragma unroll
      for (int nf = 0; nf < 4; ++nf) {
        const size_t krow = (size_t)(b * Tn + s0 + 16 * nf + l15) * Hn;
        bk[2 * nf]     = *(const bf16x8*)(kb + krow + quad * 8);
        bk[2 * nf + 1] = *(const bf16x8*)(kb + krow + 32 + quad * 8);
      }
      auto cload = [&](bf16x8& A0, bf16x8& A1, int k) {
        size_t ar = (size_t)(b * Tn + ((i + k) << 6) + 16 * w + l15) * Hn;
        A0 = *(const bf16x8*)(qb + ar + quad * 8);
        A1 = *(const bf16x8*)(qb + ar + 32 + quad * 8);
      };
      auto ccomp = [&](bf16x8 A0, bf16x8 A1, int k) {
        f32x4 sc[4] = {};
        #pragma unroll
        for (int nf = 0; nf < 4; ++nf) {
          sc[nf] = MFMA(A0, bk[2 * nf], sc[nf]);
          sc[nf] = MFMA(A1, bk[2 * nf + 1], sc[nf]);
        }
        const bool diag = (k == 0);
        const int tb = ((i + k) << 6) + 16 * w + quad * 4;
        #pragma unroll
        for (int nf = 0; nf < 4; ++nf) {
          int s = s0 + 16 * nf + l15;
          #pragma unroll
          for (int r = 0; r < 4; ++r) {
            float v = sc[nf][r] * SCALE2;            // exp2-domain score
            if (diag && (tb + r) < s) v = -INFINITY; // exp2(-inf) = 0
            l[nf] += fexp2(v);
          }
        }
      };
      bf16x8 a0A, a1A, a0B, a1B, a0C, a1C;
      cload(a0A, a1A, k0);
      if (n > 1) cload(a0B, a1B, k0 + 1);
      if (n > 2) cload(a0C, a1C, k0 + 2);
      int k = k0;
      while (k + 3 < k1) {  // 3x unrolled steady state, 2 loads in flight
        ccomp(a0A, a1A, k);     cload(a0A, a1A, k + 3);
        ccomp(a0B, a1B, k + 1); if (k + 4 < k1) cload(a0B, a1B, k + 4);
        ccomp(a0C, a1C, k + 2); if (k + 5 < k1) cload(a0C, a1C, k + 5);
        k += 3;
      }
      const int rem2 = k1 - k;
      if (rem2 > 0) ccomp(a0A, a1A, k);
      if (rem2 > 1) ccomp(a0B, a1B, k + 1);
      if (rem2 > 2) ccomp(a0C, a1C, k + 2);
    }
    __syncthreads();  // protect redl reuse across phases
    #pragma unroll
    for (int nf = 0; nf < 4; ++nf) redl[16 * nf + l15][w * 4 + quad] = l[nf];
    __syncthreads();
    if (tid < 64) {
      float ls = 0.f;
      #pragma unroll
      for (int q2 = 0; q2 < 16; ++q2) ls += redl[tid][q2];
      atomicAdd(&Lsum[b * Tn + s0 + tid], ls);  // dense column-sum layout
    }
  };
  run(j, lo, min(hi, big));                       // big member: colchunk j
  run(31 - j, max(lo, big) - big, hi - big);      // small: colchunk 31-j
}

// ---------------- K3: FUSED out = (exp(QK^T)/L)_tri . vT^T, atomic-free -----
// Block = (b = bid&7 XCD-locked, tile, half): 32 output rows, 512 blocks, 2/CU,
// heavy tiles first per XCD. Per block: rcpL[0..64*nch) precomputed into LDS.
// The tile's nch chunks split across 4 waves (stride 4); kf double-buffered
// (loads issue right after the QK MFMAs, land in the other buffer), vf single-
// buffered tail-issued. Per chunk per wave: 16 MFMA S^T=K.Q (2 strips),
// mask+exp2, *rcpL fold (P' = E/L in [0,1]), bf16-pack, per-wave XOR-swizzled
// LDS transpose (no barriers, typed u32), 16 MFMA PV against raw vT.
// Cross-wave partials reduced via LDS, one coalesced f32 store per element.
__global__ __launch_bounds__(256, 2) void outg_kernel(
    const short* __restrict__ qb, const short* __restrict__ kb,
    const short* __restrict__ vT, const float* __restrict__ Lsum,
    float* __restrict__ out) {
  const int bid = blockIdx.x;
  const int b = bid & 7;                   // XCD-locked batch
  const int rest = bid >> 3;               // 0..63
  const int tile = 31 - (rest >> 1);       // heavy (many-chunk) tiles first
  const int half = rest & 1;
  const int nch = tile + 1;
  const int tid = threadIdx.x, w = tid >> 6, l15 = tid & 15, quad = (tid & 63) >> 4;
  __shared__ unsigned plds[4][512];        // per-wave 2KB P tile [16 t][64 s] bf16
  __shared__ float red[4][32][64];         // cross-wave accumulator reduce
  __shared__ float rcpl[2048];             // 1/L[s] for this block's s-range

  const int smax = nch << 6;
  for (int s = tid; s < smax; s += 256)    // coalesced; v_rcp (~1ulp, harmless)
    rcpl[s] = frcp(Lsum[b * Tn + s]);
  __syncthreads();

  // XOR swizzle: byte ^= (l15&7)<<4 breaks the 128B-row same-bank pattern.
  const int swz = (l15 & 7) << 4;
  int wroff[8];                            // u32 offsets: s = 16nf+4q+{2p,2p+1}
  #pragma unroll
  for (int nf = 0; nf < 4; ++nf)
    #pragma unroll
    for (int p = 0; p < 2; ++p)
      wroff[2 * nf + p] = (l15 * 128 + ((nf * 32 + quad * 8 + p * 4) ^ swz)) >> 2;
  const int rd0 = (l15 * 128 + ((quad * 16) ^ swz)) >> 2;        // s = 8q..8q+7
  const int rd1 = (l15 * 128 + ((64 + quad * 16) ^ swz)) >> 2;   // s = 32+8q..+7
  const size_t QKbase = (size_t)b * Tn * Hn;
  const size_t Vbase  = (size_t)b * Hn * Tn;
  const int tbase = (tile << 6) + (half << 5);  // this block's 32 output rows
  const int tg0 = tbase + l15;                  // strip0 lane query row
  const int tg1 = tbase + 16 + l15;             // strip1 lane query row

  const size_t qrow0 = QKbase + (size_t)(tbase + l15) * Hn;
  const size_t qrow1 = qrow0 + 16 * Hn;
  const bf16x8 qf00 = *(const bf16x8*)(qb + qrow0 + quad * 8);   // B[n=t][k=h]
  const bf16x8 qf01 = *(const bf16x8*)(qb + qrow0 + 32 + quad * 8);
  const bf16x8 qf10 = *(const bf16x8*)(qb + qrow1 + quad * 8);
  const bf16x8 qf11 = *(const bf16x8*)(qb + qrow1 + 32 + quad * 8);

  f32x4 acc0[4] = {}, acc1[4] = {};
  bf16x8 kfA[8], kfB[8], vf[8];
  auto loadK = [&](bf16x8 (&kf)[8], int ch) {  // A[m=s][k=h] frags for S^T
    const int s0 = ch << 6;
    #pragma unroll
    for (int nf = 0; nf < 4; ++nf) {
      const size_t kr = QKbase + (size_t)(s0 + 16 * nf + l15) * Hn;
      kf[2 * nf]     = *(const bf16x8*)(kb + kr + quad * 8);
      kf[2 * nf + 1] = *(const bf16x8*)(kb + kr + 32 + quad * 8);
    }
  };
  auto loadV = [&](int ch) {               // B[n=h][k=s] frags for PV (raw vT)
    const int s0 = ch << 6;
    #pragma unroll
    for (int nf = 0; nf < 4; ++nf) {
      const size_t vr = Vbase + (size_t)(16 * nf + l15) * Tn + s0;
      vf[2 * nf]     = *(const bf16x8*)(vT + vr + quad * 8);
      vf[2 * nf + 1] = *(const bf16x8*)(vT + vr + 32 + quad * 8);
    }
  };
  // strip = {exp*rcpL + pack -> LDS -> read back A-frags -> 8 PV MFMA into acc}
  auto strip = [&](const f32x4 (&sc)[4], const float (&rl)[16], int s0,
                   bool diag, int tg, f32x4 (&acc)[4]) {
    #pragma unroll
    for (int nf = 0; nf < 4; ++nf) {
      float ev[4];
      #pragma unroll
      for (int r = 0; r < 4; ++r) {
        float v = sc[nf][r] * SCALE2;
        const int s = s0 + 16 * nf + quad * 4 + r;
        if (diag && tg < s) v = -INFINITY;           // causal: exp2(-inf)=0
        ev[r] = fexp2(v) * rl[nf * 4 + r];           // P' = E/L in [0,1]
      }
      plds[w][wroff[2 * nf]]     = pack2(ev[0], ev[1]);
      plds[w][wroff[2 * nf + 1]] = pack2(ev[2], ev[3]);
    }
    // typed u32 reads: may-alias with the stores above -> order preserved;
    // DS pipe in-order per wave -> data correct, no vmcnt drain.
    const bf16x8 a0 = ldp(&plds[w][rd0]);
    const bf16x8 a1 = ldp(&plds[w][rd1]);
    __builtin_amdgcn_s_setprio(1);
    #pragma unroll
    for (int nf = 0; nf < 4; ++nf) {       // D[t][h]: lane&15 = h, t = 4q+r
      acc[nf] = MFMA(a0, vf[2 * nf], acc[nf]);
      acc[nf] = MFMA(a1, vf[2 * nf + 1], acc[nf]);
    }
    __builtin_amdgcn_s_setprio(0);
  };
  auto body = [&](int ch, const bf16x8 (&CUR)[8], bf16x8 (&NXT)[8]) {
    const int s0 = ch << 6;
    const int nx = ch + 4;
    f32x4 sc0[4] = {}, sc1[4] = {};        // D[s][t]: lane&15 = t, s = 16nf+4q+r
    __builtin_amdgcn_s_setprio(1);
    #pragma unroll
    for (int nf = 0; nf < 4; ++nf) {
      sc0[nf] = MFMA(CUR[2 * nf], qf00, sc0[nf]);
      sc0[nf] = MFMA(CUR[2 * nf + 1], qf01, sc0[nf]);
    }
    #pragma unroll
    for (int nf = 0; nf < 4; ++nf) {
      sc1[nf] = MFMA(CUR[2 * nf], qf10, sc1[nf]);
      sc1[nf] = MFMA(CUR[2 * nf + 1], qf11, sc1[nf]);
    }
    __builtin_amdgcn_s_setprio(0);
    if (nx < nch) loadK(NXT, nx);          // early issue, lands in other buffer
    float rl[16];                          // rcpL regs, shared by both strips
    #pragma unroll
    for (int nf = 0; nf < 4; ++nf)
      #pragma unroll
      for (int r = 0; r < 4; ++r)
        rl[nf * 4 + r] = rcpl[s0 + 16 * nf + quad * 4 + r];
    const bool diag = (ch == tile);
    strip(sc0, rl, s0, diag, tg0, acc0);   // strip0: exp->LDS->PV
    strip(sc1, rl, s0, diag, tg1, acc1);   // strip1 reuses same LDS region
    if (nx < nch) loadV(nx);               // tail issue (vf consumed above)
  };

  if (w < nch) { loadK(kfA, w); loadV(w); }    // this wave's first owned chunk
  for (int ch = w; ch < nch; ch += 8) {    // explicit A/B ping-pong (static)
    body(ch, kfA, kfB);
    if (ch + 4 < nch) body(ch + 4, kfB, kfA);
  }

  // cross-wave reduction of the 4 partial accumulators, then one plain store
  #pragma unroll
  for (int nf = 0; nf < 4; ++nf)
    #pragma unroll
    for (int r = 0; r < 4; ++r) {
      red[w][quad * 4 + r][16 * nf + l15]      = acc0[nf][r];
      red[w][16 + quad * 4 + r][16 * nf + l15] = acc1[nf][r];
    }
  __syncthreads();
  {
    const int row = tid >> 3, c8 = (tid & 7) * 8;   // 32 rows x 8 lanes x 8 cols
    float4 t0 = {0.f, 0.f, 0.f, 0.f}, t1 = {0.f, 0.f, 0.f, 0.f};
    #pragma unroll
    for (int ww = 0; ww < 4; ++ww) {
      float4 s0 = *(const float4*)(&red[ww][row][c8]);
      float4 s1 = *(const float4*)(&red[ww][row][c8 + 4]);
      t0.x += s0.x; t0.y += s0.y; t0.z += s0.z; t0.w += s0.w;
      t1.x += s1.x; t1.y += s1.y; t1.z += s1.z; t1.w += s1.w;
    }
    float* o = &out[QKbase + (size_t)(tbase + row) * Hn + c8];
    *(float4*)(o) = t0;
    *(float4*)(o + 4) = t1;
  }
}

extern "C" void kernel_launch(void* const* d_in, const int* in_sizes, int n_in,
                              void* d_out, int out_size, void* d_ws, size_t ws_size,
                              hipStream_t stream) {
  const float* x  = (const float*)d_in[0];
  const float* Wq = (const float*)d_in[1];
  const float* Wk = (const float*)d_in[2];
  const float* Wv = (const float*)d_in[3];
  char* ws = (char*)d_ws;                          // needs ~6.6 MB
  short* qb   = (short*)(ws);                      // 2 MB (T,H)
  short* kb   = (short*)(ws + 2097152);            // 2 MB (T,H)
  short* vT   = (short*)(ws + 4194304);            // 2 MB (H,T)
  short* WbT  = (short*)(ws + 6291456);            // 144 KB
  float* Lsum = (float*)(ws + 6438912);            // 64 KB dense column sums
  float* outp = (float*)d_out;

  hipLaunchKernelGGL(wconv_kernel, dim3(288), dim3(256), 0, stream, Wq, Wk, Wv, WbT, Lsum);
  hipLaunchKernelGGL(proj_kernel, dim3(Bn * Tn / 16), dim3(256), 0, stream, x, WbT, qb, kb, vT);
  hipLaunchKernelGGL(colstats_kernel, dim3(1024), dim3(256), 0, stream, qb, kb, Lsum);
  hipLaunchKernelGGL(outg_kernel, dim3(512), dim3(256), 0, stream, qb, kb, vT, Lsum, outp);
}